// Round 3
// baseline (1431.444 us; speedup 1.0000x reference)
//
#include <hip/hip_runtime.h>
#include <math.h>

#define NB 32768
#define ND 768
#define NH 256
#define NG 8
#define GSZ 96

__device__ __forceinline__ float gelu_exact(float v) {
    return 0.5f * v * (1.0f + erff(v * 0.7071067811865475f));
}

__device__ __forceinline__ float sigmoidf_(float v) {
    return 1.0f / (1.0f + expf(-v));
}

// ---------------------------------------------------------------------------
// K1: u = x @ [w1 | dw1] ; h1 = gelu(LN(u_w1 + b1)) ; g1 = gelu(u_dw1 + db1)
// 256 threads = 4 waves. Tile 64 rows x 512 cols, K-chunk 32.
// Wave wv owns rows wv*16..+15; lane tc owns cols {tc*4..+3} of each 256-half.
// Per-thread register tile 16x8. Per k-iter: 6 b128 LDS reads, 128 FMAs
//   -> LDS 72cyc*4SIMD = 288 vs VALU 256 -> ~89% VALU cap.
// ---------------------------------------------------------------------------
__global__ __launch_bounds__(256, 2) void k1_gemm_lnx(
    const float* __restrict__ x, const float* __restrict__ w1,
    const float* __restrict__ dw1, const float* __restrict__ b1,
    const float* __restrict__ db1, const float* __restrict__ lng,
    const float* __restrict__ lnb, float* __restrict__ h1out,
    float* __restrict__ g1out)
{
    __shared__ float xs[32][64];     // [k][row]   8 KB
    __shared__ float ws[32][512];    // [k][col]  64 KB (0..255 w1, 256..511 dw1)

    const int tid = threadIdx.x;
    const int tc = tid & 63;
    const int wv = tid >> 6;
    const int c0 = tc * 4;           // col base within each 256-half
    const int r0 = wv * 16;
    const int rowsBase = blockIdx.x * 64;

    float acc[16][8];
    #pragma unroll
    for (int i = 0; i < 16; ++i)
        #pragma unroll
        for (int j = 0; j < 8; ++j) acc[i][j] = 0.0f;

    for (int kb = 0; kb < ND; kb += 32) {
        // stage x: 64 rows x 32 k -> xs[k][row]; 512 f4, 2 per thread
        #pragma unroll
        for (int m = 0; m < 2; ++m) {
            int flat = m * 256 + tid;
            int r = flat & 63, i4 = flat >> 6;   // i4 in 0..7
            float4 v = *(const float4*)(x + (size_t)(rowsBase + r) * ND + kb + i4 * 4);
            xs[i4*4+0][r] = v.x; xs[i4*4+1][r] = v.y;
            xs[i4*4+2][r] = v.z; xs[i4*4+3][r] = v.w;
        }
        // stage weights: 32 k x 512 cols; 4096 f4, 16 per thread
        #pragma unroll
        for (int m = 0; m < 16; ++m) {
            int flat = m * 256 + tid;
            int k = flat >> 7;
            int c = (flat & 127) * 4;
            float4 v;
            if (c < 256) v = *(const float4*)(w1  + (size_t)(kb + k) * 256 + c);
            else         v = *(const float4*)(dw1 + (size_t)(kb + k) * 256 + (c - 256));
            *(float4*)&ws[k][c] = v;
        }
        __syncthreads();
        #pragma unroll 4
        for (int k = 0; k < 32; ++k) {
            float xv[16], wv4[8];
            *(float4*)&xv[0]   = *(const float4*)&xs[k][r0];        // broadcast
            *(float4*)&xv[4]   = *(const float4*)&xs[k][r0 + 4];
            *(float4*)&xv[8]   = *(const float4*)&xs[k][r0 + 8];
            *(float4*)&xv[12]  = *(const float4*)&xs[k][r0 + 12];
            *(float4*)&wv4[0]  = *(const float4*)&ws[k][c0];        // spread, 2-way
            *(float4*)&wv4[4]  = *(const float4*)&ws[k][256 + c0];
            #pragma unroll
            for (int i = 0; i < 16; ++i)
                #pragma unroll
                for (int j = 0; j < 8; ++j)
                    acc[i][j] = fmaf(xv[i], wv4[j], acc[i][j]);
        }
        __syncthreads();
    }

    // biases
    float4 b1v  = *(const float4*)(b1 + c0);
    float4 db1v = *(const float4*)(db1 + c0);
    #pragma unroll
    for (int i = 0; i < 16; ++i) {
        acc[i][0] += b1v.x;  acc[i][1] += b1v.y;
        acc[i][2] += b1v.z;  acc[i][3] += b1v.w;
        acc[i][4] += db1v.x; acc[i][5] += db1v.y;
        acc[i][6] += db1v.z; acc[i][7] += db1v.w;
    }

    // LayerNorm stats over 256 w1-cols per row: wave covers all 256 (64 lanes x 4)
    float s[16], q[16];
    #pragma unroll
    for (int i = 0; i < 16; ++i) {
        s[i] = acc[i][0] + acc[i][1] + acc[i][2] + acc[i][3];
        q[i] = acc[i][0]*acc[i][0] + acc[i][1]*acc[i][1]
             + acc[i][2]*acc[i][2] + acc[i][3]*acc[i][3];
    }
    #pragma unroll
    for (int o = 1; o < 64; o <<= 1) {
        #pragma unroll
        for (int i = 0; i < 16; ++i) {
            s[i] += __shfl_xor(s[i], o);
            q[i] += __shfl_xor(q[i], o);
        }
    }

    float4 lngv = *(const float4*)(lng + c0);
    float4 lnbv = *(const float4*)(lnb + c0);
    #pragma unroll
    for (int i = 0; i < 16; ++i) {
        int row = rowsBase + r0 + i;
        float mean = s[i] * (1.0f / 256.0f);
        float var  = q[i] * (1.0f / 256.0f) - mean * mean;
        float rstd = rsqrtf(var + 1e-5f);
        float4 h;
        h.x = gelu_exact((acc[i][0] - mean) * rstd * lngv.x + lnbv.x);
        h.y = gelu_exact((acc[i][1] - mean) * rstd * lngv.y + lnbv.y);
        h.z = gelu_exact((acc[i][2] - mean) * rstd * lngv.z + lnbv.z);
        h.w = gelu_exact((acc[i][3] - mean) * rstd * lngv.w + lnbv.w);
        *(float4*)(h1out + (size_t)row * 256 + c0) = h;
        float4 g;
        g.x = gelu_exact(acc[i][4]); g.y = gelu_exact(acc[i][5]);
        g.z = gelu_exact(acc[i][6]); g.w = gelu_exact(acc[i][7]);
        *(float4*)(g1out + (size_t)row * 256 + c0) = g;
    }
}

// ---------------------------------------------------------------------------
// K2b: dwts = sigmoid(g1[B,256] @ dw2[256,768] + db2)
// 256 threads = 4 waves. Tile 64 rows x 768 cols (all cols in block), chunk 16.
// Per-thread 16x12 -> per k-iter: 7 b128 reads (84*4=336) vs 384 VALU -> 100% cap.
// ---------------------------------------------------------------------------
__global__ __launch_bounds__(256, 2) void k2_dw(
    const float* __restrict__ g1, const float* __restrict__ dw2,
    const float* __restrict__ db2, float* __restrict__ out)
{
    __shared__ float xs[16][64];     // 4 KB
    __shared__ float ws[16][768];    // 48 KB

    const int tid = threadIdx.x;
    const int tc = tid & 63;
    const int wv = tid >> 6;
    const int c0 = tc * 4;           // within each 256-block of cols
    const int r0 = wv * 16;
    const int rowsBase = blockIdx.x * 64;

    float acc[16][12];
    #pragma unroll
    for (int i = 0; i < 16; ++i)
        #pragma unroll
        for (int j = 0; j < 12; ++j) acc[i][j] = 0.0f;

    for (int kb = 0; kb < 256; kb += 16) {
        // stage g1: 64 rows x 16 k; 256 f4, 1 per thread
        {
            int r = tid & 63, i4 = tid >> 6;   // 0..3
            float4 v = *(const float4*)(g1 + (size_t)(rowsBase + r) * 256 + kb + i4 * 4);
            xs[i4*4+0][r] = v.x; xs[i4*4+1][r] = v.y;
            xs[i4*4+2][r] = v.z; xs[i4*4+3][r] = v.w;
        }
        // stage dw2: 16 k x 768 c; 3072 f4, 12 per thread
        #pragma unroll
        for (int m = 0; m < 12; ++m) {
            int flat = m * 256 + tid;
            int k = flat / 192;
            int c = (flat - k * 192) * 4;
            *(float4*)&ws[k][c] = *(const float4*)(dw2 + (size_t)(kb + k) * 768 + c);
        }
        __syncthreads();
        #pragma unroll 4
        for (int k = 0; k < 16; ++k) {
            float xv[16], wv4[12];
            *(float4*)&xv[0]  = *(const float4*)&xs[k][r0];
            *(float4*)&xv[4]  = *(const float4*)&xs[k][r0 + 4];
            *(float4*)&xv[8]  = *(const float4*)&xs[k][r0 + 8];
            *(float4*)&xv[12] = *(const float4*)&xs[k][r0 + 12];
            *(float4*)&wv4[0] = *(const float4*)&ws[k][c0];
            *(float4*)&wv4[4] = *(const float4*)&ws[k][256 + c0];
            *(float4*)&wv4[8] = *(const float4*)&ws[k][512 + c0];
            #pragma unroll
            for (int i = 0; i < 16; ++i)
                #pragma unroll
                for (int j = 0; j < 12; ++j)
                    acc[i][j] = fmaf(xv[i], wv4[j], acc[i][j]);
        }
        __syncthreads();
    }

    float4 bv0 = *(const float4*)(db2 + c0);
    float4 bv1 = *(const float4*)(db2 + 256 + c0);
    float4 bv2 = *(const float4*)(db2 + 512 + c0);
    #pragma unroll
    for (int i = 0; i < 16; ++i) {
        int row = rowsBase + r0 + i;
        float4 o0, o1, o2;
        o0.x = sigmoidf_(acc[i][0] + bv0.x);  o0.y = sigmoidf_(acc[i][1] + bv0.y);
        o0.z = sigmoidf_(acc[i][2] + bv0.z);  o0.w = sigmoidf_(acc[i][3] + bv0.w);
        o1.x = sigmoidf_(acc[i][4] + bv1.x);  o1.y = sigmoidf_(acc[i][5] + bv1.y);
        o1.z = sigmoidf_(acc[i][6] + bv1.z);  o1.w = sigmoidf_(acc[i][7] + bv1.w);
        o2.x = sigmoidf_(acc[i][8] + bv2.x);  o2.y = sigmoidf_(acc[i][9] + bv2.y);
        o2.z = sigmoidf_(acc[i][10] + bv2.z); o2.w = sigmoidf_(acc[i][11] + bv2.w);
        *(float4*)(out + (size_t)row * 768 + c0)       = o0;
        *(float4*)(out + (size_t)row * 768 + 256 + c0) = o1;
        *(float4*)(out + (size_t)row * 768 + 512 + c0) = o2;
    }
}

// ---------------------------------------------------------------------------
// K2a: h2 = gelu(h1[B,256] @ w2[256,128] + b2), tile 128x128, 8x8/thread.
// ---------------------------------------------------------------------------
__global__ __launch_bounds__(256, 4) void k2_gemm(
    const float* __restrict__ A, const float* __restrict__ W,
    const float* __restrict__ bias, float* __restrict__ out)
{
    __shared__ float xs[32][128];
    __shared__ float ws[32][128];

    const int tid = threadIdx.x;
    const int tc = tid & 15;
    const int tr = tid >> 4;
    const int c0 = tc * 4;
    const int c1 = 64 + tc * 4;
    const int r0 = tr * 8;
    const int rowsBase = blockIdx.x * 128;

    float acc[8][8];
    #pragma unroll
    for (int i = 0; i < 8; ++i)
        #pragma unroll
        for (int j = 0; j < 8; ++j) acc[i][j] = 0.0f;

    for (int kb = 0; kb < 256; kb += 32) {
        #pragma unroll
        for (int m = 0; m < 4; ++m) {
            int flat = m * 256 + tid;
            int r = flat >> 3, i4 = flat & 7;
            float4 v = *(const float4*)(A + (size_t)(rowsBase + r) * 256 + kb + i4 * 4);
            xs[i4*4+0][r] = v.x; xs[i4*4+1][r] = v.y;
            xs[i4*4+2][r] = v.z; xs[i4*4+3][r] = v.w;
        }
        #pragma unroll
        for (int m = 0; m < 4; ++m) {
            int flat = m * 256 + tid;
            int k = flat >> 5;
            int c = (flat & 31) * 4;
            *(float4*)&ws[k][c] = *(const float4*)(W + (size_t)(kb + k) * 128 + c);
        }
        __syncthreads();
        #pragma unroll 8
        for (int k = 0; k < 32; ++k) {
            float xv[8], wv4[8];
            *(float4*)&xv[0]  = *(const float4*)&xs[k][r0];
            *(float4*)&xv[4]  = *(const float4*)&xs[k][r0 + 4];
            *(float4*)&wv4[0] = *(const float4*)&ws[k][c0];
            *(float4*)&wv4[4] = *(const float4*)&ws[k][c1];
            #pragma unroll
            for (int i = 0; i < 8; ++i)
                #pragma unroll
                for (int j = 0; j < 8; ++j)
                    acc[i][j] = fmaf(xv[i], wv4[j], acc[i][j]);
        }
        __syncthreads();
    }

    float4 bv0 = *(const float4*)(bias + c0);
    float4 bv1 = *(const float4*)(bias + c1);
    #pragma unroll
    for (int i = 0; i < 8; ++i) {
        int row = rowsBase + r0 + i;
        float o[8];
        o[0] = acc[i][0] + bv0.x; o[1] = acc[i][1] + bv0.y;
        o[2] = acc[i][2] + bv0.z; o[3] = acc[i][3] + bv0.w;
        o[4] = acc[i][4] + bv1.x; o[5] = acc[i][5] + bv1.y;
        o[6] = acc[i][6] + bv1.z; o[7] = acc[i][7] + bv1.w;
        #pragma unroll
        for (int j = 0; j < 8; ++j) o[j] = gelu_exact(o[j]);
        *(float4*)(out + (size_t)row * 128 + c0) = *(float4*)&o[0];
        *(float4*)(out + (size_t)row * 128 + c1) = *(float4*)&o[4];
    }
}

// ---------------------------------------------------------------------------
// K3: logits = h2 @ w3 + b3 + gi; probs; constrained selection -> sel; scalars.
// scal: [0]=active_groups [1..8]=group_usage [9]=load_balance [10]=active_dims
// ---------------------------------------------------------------------------
__global__ __launch_bounds__(128) void k3_router(
    const float* __restrict__ h2, const float* __restrict__ w3,
    const float* __restrict__ b3, const float* __restrict__ gi,
    float* __restrict__ probsOut, float* __restrict__ selOut,
    float* __restrict__ scal)
{
    __shared__ float ws3[128][8];
    __shared__ float sAct[2], sP[2], sCnt[2][8];

    const int tid = threadIdx.x;
    *(float4*)&ws3[tid][0] = *(const float4*)(w3 + tid * 8);
    *(float4*)&ws3[tid][4] = *(const float4*)(w3 + tid * 8 + 4);
    __syncthreads();

    const int row = blockIdx.x * 128 + tid;
    const float* h2r = h2 + (size_t)row * 128;

    float accg[8];
    #pragma unroll
    for (int g = 0; g < 8; ++g) accg[g] = 0.0f;
    #pragma unroll 8
    for (int k4 = 0; k4 < 32; ++k4) {
        float4 hv = *(const float4*)(h2r + k4 * 4);
        float hv4[4] = {hv.x, hv.y, hv.z, hv.w};
        #pragma unroll
        for (int t = 0; t < 4; ++t)
            #pragma unroll
            for (int g = 0; g < 8; ++g)
                accg[g] = fmaf(hv4[t], ws3[k4 * 4 + t][g], accg[g]);
    }

    float p[8], gs[8], cnt[8];
    float actCnt = 0.0f, pSum = 0.0f;
    #pragma unroll
    for (int g = 0; g < 8; ++g) {
        float lg = accg[g] + b3[g] + gi[g];
        p[g] = sigmoidf_(lg);
    }
    #pragma unroll
    for (int g = 0; g < 8; ++g) {
        int rank = 0;
        #pragma unroll
        for (int j = 0; j < 8; ++j) {
            rank += (p[j] > p[g]) ? 1 : 0;
            rank += (j < g && p[j] == p[g]) ? 1 : 0;
        }
        float act = (rank < 2) ? 1.0f
                  : ((rank < 6) ? ((p[g] > 0.5f) ? 1.0f : 0.0f) : 0.0f);
        gs[g] = (act - p[g]) + p[g];
        float over = (p[g] > 0.5f) ? 1.0f : 0.0f;
        cnt[g] = over;
        actCnt += over;
        pSum += p[g];
    }

    *(float4*)(probsOut + (size_t)row * 8)     = *(float4*)&p[0];
    *(float4*)(probsOut + (size_t)row * 8 + 4) = *(float4*)&p[4];
    *(float4*)(selOut   + (size_t)row * 8)     = *(float4*)&gs[0];
    *(float4*)(selOut   + (size_t)row * 8 + 4) = *(float4*)&gs[4];

    #pragma unroll
    for (int o = 32; o > 0; o >>= 1) {
        actCnt += __shfl_down(actCnt, o);
        pSum   += __shfl_down(pSum, o);
        #pragma unroll
        for (int g = 0; g < 8; ++g) cnt[g] += __shfl_down(cnt[g], o);
    }
    if ((tid & 63) == 0) {
        int w = tid >> 6;
        sAct[w] = actCnt; sP[w] = pSum;
        #pragma unroll
        for (int g = 0; g < 8; ++g) sCnt[w][g] = cnt[g];
    }
    __syncthreads();
    if (tid == 0) {
        const float invB = 1.0f / 32768.0f;
        atomicAdd(&scal[0], (sAct[0] + sAct[1]) * invB);
        atomicAdd(&scal[9], (sP[0] + sP[1]) * invB);
        #pragma unroll
        for (int g = 0; g < 8; ++g)
            atomicAdd(&scal[1 + g], (sCnt[0][g] + sCnt[1][g]) * invB);
    }
}

// ---------------------------------------------------------------------------
// K4: gmask = repeat(sel); mask = gmask * dwts; active_dims reduce
// ---------------------------------------------------------------------------
__global__ __launch_bounds__(256) void k4_mask(
    const float* __restrict__ sel, const float* __restrict__ dwts,
    float* __restrict__ gmaskOut, float* __restrict__ maskOut,
    float* __restrict__ activeDims)
{
    const int stride = gridDim.x * 256;
    float cntF = 0.0f;
    for (int i4 = blockIdx.x * 256 + threadIdx.x; i4 < 6291456; i4 += stride) {
        int row = i4 / 192;
        int rem = i4 - row * 192;
        int g = rem / 24;
        float v = sel[(size_t)row * 8 + g];
        float4 d = *(const float4*)(dwts + (size_t)i4 * 4);
        float4 gm = {v, v, v, v};
        float4 m = {v * d.x, v * d.y, v * d.z, v * d.w};
        *(float4*)(gmaskOut + (size_t)i4 * 4) = gm;
        *(float4*)(maskOut  + (size_t)i4 * 4) = m;
        cntF += (m.x > 0.5f ? 1.0f : 0.0f) + (m.y > 0.5f ? 1.0f : 0.0f)
              + (m.z > 0.5f ? 1.0f : 0.0f) + (m.w > 0.5f ? 1.0f : 0.0f);
    }
    #pragma unroll
    for (int o = 32; o > 0; o >>= 1) cntF += __shfl_down(cntF, o);
    __shared__ float sc[4];
    if ((threadIdx.x & 63) == 0) sc[threadIdx.x >> 6] = cntF;
    __syncthreads();
    if (threadIdx.x == 0)
        atomicAdd(activeDims, (sc[0] + sc[1] + sc[2] + sc[3]) * (1.0f / 32768.0f));
}

__global__ void kz_zero(float* s) { if (threadIdx.x < 11) s[threadIdx.x] = 0.0f; }

// ---------------------------------------------------------------------------
extern "C" void kernel_launch(void* const* d_in, const int* in_sizes, int n_in,
                              void* d_out, int out_size, void* d_ws, size_t ws_size,
                              hipStream_t stream)
{
    const float* x   = (const float*)d_in[0];
    const float* w1  = (const float*)d_in[1];
    const float* b1  = (const float*)d_in[2];
    const float* lng = (const float*)d_in[3];
    const float* lnb = (const float*)d_in[4];
    const float* w2  = (const float*)d_in[5];
    const float* b2  = (const float*)d_in[6];
    const float* w3  = (const float*)d_in[7];
    const float* b3  = (const float*)d_in[8];
    const float* dw1 = (const float*)d_in[9];
    const float* db1 = (const float*)d_in[10];
    const float* dw2 = (const float*)d_in[11];
    const float* db2 = (const float*)d_in[12];
    const float* gi  = (const float*)d_in[13];

    float* out   = (float*)d_out;
    float* mask  = out;                 // [B,768]
    float* gmask = out + 25165824;      // [B,768]
    float* dwts  = out + 50331648;      // [B,768]
    float* probs = out + 75497472;      // [B,8]
    float* sel   = out + 75759616;      // [B,8]
    float* scal  = out + 76021760;      // 11 scalars

    // scratch inside the mask slot (overwritten by k4 last)
    float* h1 = mask;                   // [B,256]
    float* g1 = mask + 8388608;         // [B,256]
    float* h2 = mask + 16777216;        // [B,128]

    kz_zero<<<dim3(1), dim3(64), 0, stream>>>(scal);
    k1_gemm_lnx<<<dim3(512), dim3(256), 0, stream>>>(
        x, w1, dw1, b1, db1, lng, lnb, h1, g1);
    k2_gemm<<<dim3(256), dim3(256), 0, stream>>>(h1, w2, b2, h2);
    k2_dw<<<dim3(512), dim3(256), 0, stream>>>(g1, dw2, db2, dwts);
    k3_router<<<dim3(256), dim3(128), 0, stream>>>(
        h2, w3, b3, gi, probs, sel, scal);
    k4_mask<<<dim3(2048), dim3(256), 0, stream>>>(sel, dwts, gmask, mask, &scal[10]);
}

// Round 4
// 645.946 us; speedup vs baseline: 2.2160x; 2.2160x over previous
//
#include <hip/hip_runtime.h>
#include <math.h>

#define NB 32768
#define ND 768
#define NH 256
#define NG 8
#define GSZ 96

__device__ __forceinline__ float gelu_exact(float v) {
    return 0.5f * v * (1.0f + erff(v * 0.7071067811865475f));
}

__device__ __forceinline__ float sigmoidf_(float v) {
    return 1.0f / (1.0f + expf(-v));
}

// ---------------------------------------------------------------------------
// K1: u = x @ [w1 | dw1] ; h1 = gelu(LN(u_w1 + b1)) ; g1 = gelu(u_dw1 + db1)
// 512 threads = 8 waves. Tile 128 rows x 512 cols, K-chunk 32.
// Wave wv owns rows wv*16..+15; lane tc owns cols {tc*4..+3} of each 256-half.
// Per-thread 16x8 (acc=128). Per k-iter: 6 b128 reads (72 LDS-cyc x4 SIMD=288)
// vs 256 VALU-cyc -> 89% VALU cap. NO min-occupancy launch bound (spill trap).
// ---------------------------------------------------------------------------
__global__ __launch_bounds__(512) void k1_gemm_lnx(
    const float* __restrict__ x, const float* __restrict__ w1,
    const float* __restrict__ dw1, const float* __restrict__ b1,
    const float* __restrict__ db1, const float* __restrict__ lng,
    const float* __restrict__ lnb, float* __restrict__ h1out,
    float* __restrict__ g1out)
{
    __shared__ float xs[32][132];    // [k][row] padded: f4-aligned, staging banks spread
    __shared__ float ws[32][512];    // [k][col] 64 KB (0..255 w1, 256..511 dw1)

    const int tid = threadIdx.x;
    const int tc = tid & 63;
    const int wv = tid >> 6;         // 0..7
    const int c0 = tc * 4;           // col base within each 256-half
    const int r0 = wv * 16;
    const int rowsBase = blockIdx.x * 128;

    float acc[16][8];
    #pragma unroll
    for (int i = 0; i < 16; ++i)
        #pragma unroll
        for (int j = 0; j < 8; ++j) acc[i][j] = 0.0f;

    for (int kb = 0; kb < ND; kb += 32) {
        // stage x: 128 rows x 32 k -> xs[k][row]; 1024 f4, 2 per thread
        #pragma unroll
        for (int m = 0; m < 2; ++m) {
            int flat = m * 512 + tid;
            int r = flat >> 3, i4 = flat & 7;
            float4 v = *(const float4*)(x + (size_t)(rowsBase + r) * ND + kb + i4 * 4);
            xs[i4*4+0][r] = v.x; xs[i4*4+1][r] = v.y;
            xs[i4*4+2][r] = v.z; xs[i4*4+3][r] = v.w;
        }
        // stage weights: 32 k x 512 cols; 4096 f4, 8 per thread
        #pragma unroll
        for (int m = 0; m < 8; ++m) {
            int flat = m * 512 + tid;
            int k = flat >> 7;
            int c = (flat & 127) * 4;
            float4 v;
            if (c < 256) v = *(const float4*)(w1  + (size_t)(kb + k) * 256 + c);
            else         v = *(const float4*)(dw1 + (size_t)(kb + k) * 256 + (c - 256));
            *(float4*)&ws[k][c] = v;
        }
        __syncthreads();
        #pragma unroll 4
        for (int k = 0; k < 32; ++k) {
            float xv[16], wv4[8];
            *(float4*)&xv[0]   = *(const float4*)&xs[k][r0];        // broadcast
            *(float4*)&xv[4]   = *(const float4*)&xs[k][r0 + 4];
            *(float4*)&xv[8]   = *(const float4*)&xs[k][r0 + 8];
            *(float4*)&xv[12]  = *(const float4*)&xs[k][r0 + 12];
            *(float4*)&wv4[0]  = *(const float4*)&ws[k][c0];        // 2 lanes/bank: free
            *(float4*)&wv4[4]  = *(const float4*)&ws[k][256 + c0];
            #pragma unroll
            for (int i = 0; i < 16; ++i)
                #pragma unroll
                for (int j = 0; j < 8; ++j)
                    acc[i][j] = fmaf(xv[i], wv4[j], acc[i][j]);
        }
        __syncthreads();
    }

    // biases
    float4 b1v  = *(const float4*)(b1 + c0);
    float4 db1v = *(const float4*)(db1 + c0);
    #pragma unroll
    for (int i = 0; i < 16; ++i) {
        acc[i][0] += b1v.x;  acc[i][1] += b1v.y;
        acc[i][2] += b1v.z;  acc[i][3] += b1v.w;
        acc[i][4] += db1v.x; acc[i][5] += db1v.y;
        acc[i][6] += db1v.z; acc[i][7] += db1v.w;
    }

    // LayerNorm stats over 256 w1-cols per row: 64 lanes x 4 cols = full row
    float s[16], q[16];
    #pragma unroll
    for (int i = 0; i < 16; ++i) {
        s[i] = acc[i][0] + acc[i][1] + acc[i][2] + acc[i][3];
        q[i] = acc[i][0]*acc[i][0] + acc[i][1]*acc[i][1]
             + acc[i][2]*acc[i][2] + acc[i][3]*acc[i][3];
    }
    #pragma unroll
    for (int o = 1; o < 64; o <<= 1) {
        #pragma unroll
        for (int i = 0; i < 16; ++i) {
            s[i] += __shfl_xor(s[i], o);
            q[i] += __shfl_xor(q[i], o);
        }
    }

    float4 lngv = *(const float4*)(lng + c0);
    float4 lnbv = *(const float4*)(lnb + c0);
    #pragma unroll
    for (int i = 0; i < 16; ++i) {
        int row = rowsBase + r0 + i;
        float mean = s[i] * (1.0f / 256.0f);
        float var  = q[i] * (1.0f / 256.0f) - mean * mean;
        float rstd = rsqrtf(var + 1e-5f);
        float4 h;
        h.x = gelu_exact((acc[i][0] - mean) * rstd * lngv.x + lnbv.x);
        h.y = gelu_exact((acc[i][1] - mean) * rstd * lngv.y + lnbv.y);
        h.z = gelu_exact((acc[i][2] - mean) * rstd * lngv.z + lnbv.z);
        h.w = gelu_exact((acc[i][3] - mean) * rstd * lngv.w + lnbv.w);
        *(float4*)(h1out + (size_t)row * 256 + c0) = h;
        float4 g;
        g.x = gelu_exact(acc[i][4]); g.y = gelu_exact(acc[i][5]);
        g.z = gelu_exact(acc[i][6]); g.w = gelu_exact(acc[i][7]);
        *(float4*)(g1out + (size_t)row * 256 + c0) = g;
    }
}

// ---------------------------------------------------------------------------
// K2b: dwts = sigmoid(g1[B,256] @ dw2[256,768] + db2)
// 512 threads = 8 waves. Tile 64 rows x 768 cols, K-chunk 16.
// Wave wv owns rows wv*8..+7; lane tc owns cols {tc*4..+3} of each 256-third.
// Per-thread 8x12 (acc=96). Per k-iter: 5 b128 (240 LDS-cyc) vs 192 VALU -> 80% cap.
// ---------------------------------------------------------------------------
__global__ __launch_bounds__(512) void k2_dw(
    const float* __restrict__ g1, const float* __restrict__ dw2,
    const float* __restrict__ db2, float* __restrict__ out)
{
    __shared__ float xs[16][68];     // padded
    __shared__ float ws[16][768];    // 48 KB

    const int tid = threadIdx.x;
    const int tc = tid & 63;
    const int wv = tid >> 6;         // 0..7
    const int c0 = tc * 4;
    const int r0 = wv * 8;
    const int rowsBase = blockIdx.x * 64;

    float acc[8][12];
    #pragma unroll
    for (int i = 0; i < 8; ++i)
        #pragma unroll
        for (int j = 0; j < 12; ++j) acc[i][j] = 0.0f;

    for (int kb = 0; kb < 256; kb += 16) {
        // stage g1: 64 rows x 16 k; 256 f4, threads 0..255
        if (tid < 256) {
            int r = tid & 63, i4 = tid >> 6;   // 0..3
            float4 v = *(const float4*)(g1 + (size_t)(rowsBase + r) * 256 + kb + i4 * 4);
            xs[i4*4+0][r] = v.x; xs[i4*4+1][r] = v.y;
            xs[i4*4+2][r] = v.z; xs[i4*4+3][r] = v.w;
        }
        // stage dw2: 16 k x 768 c; 3072 f4, 6 per thread
        #pragma unroll
        for (int m = 0; m < 6; ++m) {
            int flat = m * 512 + tid;
            int k = flat / 192;
            int c = (flat - k * 192) * 4;
            *(float4*)&ws[k][c] = *(const float4*)(dw2 + (size_t)(kb + k) * 768 + c);
        }
        __syncthreads();
        #pragma unroll 4
        for (int k = 0; k < 16; ++k) {
            float xv[8], wv4[12];
            *(float4*)&xv[0]  = *(const float4*)&xs[k][r0];        // broadcast
            *(float4*)&xv[4]  = *(const float4*)&xs[k][r0 + 4];
            *(float4*)&wv4[0] = *(const float4*)&ws[k][c0];
            *(float4*)&wv4[4] = *(const float4*)&ws[k][256 + c0];
            *(float4*)&wv4[8] = *(const float4*)&ws[k][512 + c0];
            #pragma unroll
            for (int i = 0; i < 8; ++i)
                #pragma unroll
                for (int j = 0; j < 12; ++j)
                    acc[i][j] = fmaf(xv[i], wv4[j], acc[i][j]);
        }
        __syncthreads();
    }

    float4 bv0 = *(const float4*)(db2 + c0);
    float4 bv1 = *(const float4*)(db2 + 256 + c0);
    float4 bv2 = *(const float4*)(db2 + 512 + c0);
    #pragma unroll
    for (int i = 0; i < 8; ++i) {
        int row = rowsBase + r0 + i;
        float4 o0, o1, o2;
        o0.x = sigmoidf_(acc[i][0] + bv0.x);  o0.y = sigmoidf_(acc[i][1] + bv0.y);
        o0.z = sigmoidf_(acc[i][2] + bv0.z);  o0.w = sigmoidf_(acc[i][3] + bv0.w);
        o1.x = sigmoidf_(acc[i][4] + bv1.x);  o1.y = sigmoidf_(acc[i][5] + bv1.y);
        o1.z = sigmoidf_(acc[i][6] + bv1.z);  o1.w = sigmoidf_(acc[i][7] + bv1.w);
        o2.x = sigmoidf_(acc[i][8] + bv2.x);  o2.y = sigmoidf_(acc[i][9] + bv2.y);
        o2.z = sigmoidf_(acc[i][10] + bv2.z); o2.w = sigmoidf_(acc[i][11] + bv2.w);
        *(float4*)(out + (size_t)row * 768 + c0)       = o0;
        *(float4*)(out + (size_t)row * 768 + 256 + c0) = o1;
        *(float4*)(out + (size_t)row * 768 + 512 + c0) = o2;
    }
}

// ---------------------------------------------------------------------------
// K2a: h2 = gelu(h1[B,256] @ w2[256,128] + b2), tile 128x128, 8x8/thread.
// ---------------------------------------------------------------------------
__global__ __launch_bounds__(256, 4) void k2_gemm(
    const float* __restrict__ A, const float* __restrict__ W,
    const float* __restrict__ bias, float* __restrict__ out)
{
    __shared__ float xs[32][128];
    __shared__ float ws[32][128];

    const int tid = threadIdx.x;
    const int tc = tid & 15;
    const int tr = tid >> 4;
    const int c0 = tc * 4;
    const int c1 = 64 + tc * 4;
    const int r0 = tr * 8;
    const int rowsBase = blockIdx.x * 128;

    float acc[8][8];
    #pragma unroll
    for (int i = 0; i < 8; ++i)
        #pragma unroll
        for (int j = 0; j < 8; ++j) acc[i][j] = 0.0f;

    for (int kb = 0; kb < 256; kb += 32) {
        #pragma unroll
        for (int m = 0; m < 4; ++m) {
            int flat = m * 256 + tid;
            int r = flat >> 3, i4 = flat & 7;
            float4 v = *(const float4*)(A + (size_t)(rowsBase + r) * 256 + kb + i4 * 4);
            xs[i4*4+0][r] = v.x; xs[i4*4+1][r] = v.y;
            xs[i4*4+2][r] = v.z; xs[i4*4+3][r] = v.w;
        }
        #pragma unroll
        for (int m = 0; m < 4; ++m) {
            int flat = m * 256 + tid;
            int k = flat >> 5;
            int c = (flat & 31) * 4;
            *(float4*)&ws[k][c] = *(const float4*)(W + (size_t)(kb + k) * 128 + c);
        }
        __syncthreads();
        #pragma unroll 8
        for (int k = 0; k < 32; ++k) {
            float xv[8], wv4[8];
            *(float4*)&xv[0]  = *(const float4*)&xs[k][r0];
            *(float4*)&xv[4]  = *(const float4*)&xs[k][r0 + 4];
            *(float4*)&wv4[0] = *(const float4*)&ws[k][c0];
            *(float4*)&wv4[4] = *(const float4*)&ws[k][c1];
            #pragma unroll
            for (int i = 0; i < 8; ++i)
                #pragma unroll
                for (int j = 0; j < 8; ++j)
                    acc[i][j] = fmaf(xv[i], wv4[j], acc[i][j]);
        }
        __syncthreads();
    }

    float4 bv0 = *(const float4*)(bias + c0);
    float4 bv1 = *(const float4*)(bias + c1);
    #pragma unroll
    for (int i = 0; i < 8; ++i) {
        int row = rowsBase + r0 + i;
        float o[8];
        o[0] = acc[i][0] + bv0.x; o[1] = acc[i][1] + bv0.y;
        o[2] = acc[i][2] + bv0.z; o[3] = acc[i][3] + bv0.w;
        o[4] = acc[i][4] + bv1.x; o[5] = acc[i][5] + bv1.y;
        o[6] = acc[i][6] + bv1.z; o[7] = acc[i][7] + bv1.w;
        #pragma unroll
        for (int j = 0; j < 8; ++j) o[j] = gelu_exact(o[j]);
        *(float4*)(out + (size_t)row * 128 + c0) = *(float4*)&o[0];
        *(float4*)(out + (size_t)row * 128 + c1) = *(float4*)&o[4];
    }
}

// ---------------------------------------------------------------------------
// K3: logits = h2 @ w3 + b3 + gi; probs; constrained selection -> sel; scalars.
// scal: [0]=active_groups [1..8]=group_usage [9]=load_balance [10]=active_dims
// ---------------------------------------------------------------------------
__global__ __launch_bounds__(128) void k3_router(
    const float* __restrict__ h2, const float* __restrict__ w3,
    const float* __restrict__ b3, const float* __restrict__ gi,
    float* __restrict__ probsOut, float* __restrict__ selOut,
    float* __restrict__ scal)
{
    __shared__ float ws3[128][8];
    __shared__ float sAct[2], sP[2], sCnt[2][8];

    const int tid = threadIdx.x;
    *(float4*)&ws3[tid][0] = *(const float4*)(w3 + tid * 8);
    *(float4*)&ws3[tid][4] = *(const float4*)(w3 + tid * 8 + 4);
    __syncthreads();

    const int row = blockIdx.x * 128 + tid;
    const float* h2r = h2 + (size_t)row * 128;

    float accg[8];
    #pragma unroll
    for (int g = 0; g < 8; ++g) accg[g] = 0.0f;
    #pragma unroll 8
    for (int k4 = 0; k4 < 32; ++k4) {
        float4 hv = *(const float4*)(h2r + k4 * 4);
        float hv4[4] = {hv.x, hv.y, hv.z, hv.w};
        #pragma unroll
        for (int t = 0; t < 4; ++t)
            #pragma unroll
            for (int g = 0; g < 8; ++g)
                accg[g] = fmaf(hv4[t], ws3[k4 * 4 + t][g], accg[g]);
    }

    float p[8], gs[8], cnt[8];
    float actCnt = 0.0f, pSum = 0.0f;
    #pragma unroll
    for (int g = 0; g < 8; ++g) {
        float lg = accg[g] + b3[g] + gi[g];
        p[g] = sigmoidf_(lg);
    }
    #pragma unroll
    for (int g = 0; g < 8; ++g) {
        int rank = 0;
        #pragma unroll
        for (int j = 0; j < 8; ++j) {
            rank += (p[j] > p[g]) ? 1 : 0;
            rank += (j < g && p[j] == p[g]) ? 1 : 0;
        }
        float act = (rank < 2) ? 1.0f
                  : ((rank < 6) ? ((p[g] > 0.5f) ? 1.0f : 0.0f) : 0.0f);
        gs[g] = (act - p[g]) + p[g];
        float over = (p[g] > 0.5f) ? 1.0f : 0.0f;
        cnt[g] = over;
        actCnt += over;
        pSum += p[g];
    }

    *(float4*)(probsOut + (size_t)row * 8)     = *(float4*)&p[0];
    *(float4*)(probsOut + (size_t)row * 8 + 4) = *(float4*)&p[4];
    *(float4*)(selOut   + (size_t)row * 8)     = *(float4*)&gs[0];
    *(float4*)(selOut   + (size_t)row * 8 + 4) = *(float4*)&gs[4];

    #pragma unroll
    for (int o = 32; o > 0; o >>= 1) {
        actCnt += __shfl_down(actCnt, o);
        pSum   += __shfl_down(pSum, o);
        #pragma unroll
        for (int g = 0; g < 8; ++g) cnt[g] += __shfl_down(cnt[g], o);
    }
    if ((tid & 63) == 0) {
        int w = tid >> 6;
        sAct[w] = actCnt; sP[w] = pSum;
        #pragma unroll
        for (int g = 0; g < 8; ++g) sCnt[w][g] = cnt[g];
    }
    __syncthreads();
    if (tid == 0) {
        const float invB = 1.0f / 32768.0f;
        atomicAdd(&scal[0], (sAct[0] + sAct[1]) * invB);
        atomicAdd(&scal[9], (sP[0] + sP[1]) * invB);
        #pragma unroll
        for (int g = 0; g < 8; ++g)
            atomicAdd(&scal[1 + g], (sCnt[0][g] + sCnt[1][g]) * invB);
    }
}

// ---------------------------------------------------------------------------
// K4: gmask = repeat(sel); mask = gmask * dwts; active_dims reduce
// ---------------------------------------------------------------------------
__global__ __launch_bounds__(256) void k4_mask(
    const float* __restrict__ sel, const float* __restrict__ dwts,
    float* __restrict__ gmaskOut, float* __restrict__ maskOut,
    float* __restrict__ activeDims)
{
    const int stride = gridDim.x * 256;
    float cntF = 0.0f;
    for (int i4 = blockIdx.x * 256 + threadIdx.x; i4 < 6291456; i4 += stride) {
        int row = i4 / 192;
        int rem = i4 - row * 192;
        int g = rem / 24;
        float v = sel[(size_t)row * 8 + g];
        float4 d = *(const float4*)(dwts + (size_t)i4 * 4);
        float4 gm = {v, v, v, v};
        float4 m = {v * d.x, v * d.y, v * d.z, v * d.w};
        *(float4*)(gmaskOut + (size_t)i4 * 4) = gm;
        *(float4*)(maskOut  + (size_t)i4 * 4) = m;
        cntF += (m.x > 0.5f ? 1.0f : 0.0f) + (m.y > 0.5f ? 1.0f : 0.0f)
              + (m.z > 0.5f ? 1.0f : 0.0f) + (m.w > 0.5f ? 1.0f : 0.0f);
    }
    #pragma unroll
    for (int o = 32; o > 0; o >>= 1) cntF += __shfl_down(cntF, o);
    __shared__ float sc[4];
    if ((threadIdx.x & 63) == 0) sc[threadIdx.x >> 6] = cntF;
    __syncthreads();
    if (threadIdx.x == 0)
        atomicAdd(activeDims, (sc[0] + sc[1] + sc[2] + sc[3]) * (1.0f / 32768.0f));
}

__global__ void kz_zero(float* s) { if (threadIdx.x < 11) s[threadIdx.x] = 0.0f; }

// ---------------------------------------------------------------------------
extern "C" void kernel_launch(void* const* d_in, const int* in_sizes, int n_in,
                              void* d_out, int out_size, void* d_ws, size_t ws_size,
                              hipStream_t stream)
{
    const float* x   = (const float*)d_in[0];
    const float* w1  = (const float*)d_in[1];
    const float* b1  = (const float*)d_in[2];
    const float* lng = (const float*)d_in[3];
    const float* lnb = (const float*)d_in[4];
    const float* w2  = (const float*)d_in[5];
    const float* b2  = (const float*)d_in[6];
    const float* w3  = (const float*)d_in[7];
    const float* b3  = (const float*)d_in[8];
    const float* dw1 = (const float*)d_in[9];
    const float* db1 = (const float*)d_in[10];
    const float* dw2 = (const float*)d_in[11];
    const float* db2 = (const float*)d_in[12];
    const float* gi  = (const float*)d_in[13];

    float* out   = (float*)d_out;
    float* mask  = out;                 // [B,768]
    float* gmask = out + 25165824;      // [B,768]
    float* dwts  = out + 50331648;      // [B,768]
    float* probs = out + 75497472;      // [B,8]
    float* sel   = out + 75759616;      // [B,8]
    float* scal  = out + 76021760;      // 11 scalars

    // scratch inside the mask slot (overwritten by k4 last)
    float* h1 = mask;                   // [B,256]
    float* g1 = mask + 8388608;         // [B,256]
    float* h2 = mask + 16777216;        // [B,128]

    kz_zero<<<dim3(1), dim3(64), 0, stream>>>(scal);
    k1_gemm_lnx<<<dim3(256), dim3(512), 0, stream>>>(
        x, w1, dw1, b1, db1, lng, lnb, h1, g1);
    k2_gemm<<<dim3(256), dim3(256), 0, stream>>>(h1, w2, b2, h2);
    k2_dw<<<dim3(512), dim3(512), 0, stream>>>(g1, dw2, db2, dwts);
    k3_router<<<dim3(256), dim3(128), 0, stream>>>(
        h2, w3, b3, gi, probs, sel, scal);
    k4_mask<<<dim3(2048), dim3(256), 0, stream>>>(sel, dwts, gmask, mask, &scal[10]);
}

// Round 5
// 461.322 us; speedup vs baseline: 3.1029x; 1.4002x over previous
//
#include <hip/hip_runtime.h>
#include <math.h>

#define NB 32768
#define ND 768
#define NH 256
#define NG 8
#define GSZ 96

typedef __attribute__((ext_vector_type(8))) short short8_t;
typedef __attribute__((ext_vector_type(4))) float f32x4;

__device__ __forceinline__ float gelu_exact(float v) {
    return 0.5f * v * (1.0f + erff(v * 0.7071067811865475f));
}
__device__ __forceinline__ float sigmoidf_(float v) {
    return 1.0f / (1.0f + expf(-v));
}
// fp32 -> bf16 hi/lo split (RNE both)
__device__ __forceinline__ void f2bf2(float f, short& hi, short& lo) {
    union { float f; unsigned u; } a; a.f = f;
    unsigned r = a.u + 0x7FFF + ((a.u >> 16) & 1);
    hi = (short)(r >> 16);
    union { unsigned u; float f; } hf; hf.u = (r >> 16) << 16;
    union { float f; unsigned u; } b; b.f = f - hf.f;
    unsigned r2 = b.u + 0x7FFF + ((b.u >> 16) & 1);
    lo = (short)(r2 >> 16);
}

// ---------------------------------------------------------------------------
// k1r_p: partial u1 = x[:, kh] @ w1[kh, :]  (fp32, K-split 2, no bias)
// 256 thr = 4 waves; tile 128 rows x 256 cols; per-lane 16x8 (lane halves
// split rows). grid 512 -> 2 blocks/CU for overlap.
// ---------------------------------------------------------------------------
__global__ __launch_bounds__(256) void k1r_p(
    const float* __restrict__ x, const float* __restrict__ w1,
    float* __restrict__ u1p)
{
    __shared__ float xs[32][132];
    __shared__ float ws[32][256];

    const int tid = threadIdx.x;
    const int l = tid & 63;
    const int wv = tid >> 6;
    const int h = l >> 5;
    const int cl = l & 31;
    const int c0 = cl * 8;
    const int r0w = wv * 32 + h * 16;
    const int rb = blockIdx.x >> 1;
    const int half = blockIdx.x & 1;
    const int rowsBase = rb * 128;
    const int kBase = half * 384;

    float acc[16][8];
    #pragma unroll
    for (int i = 0; i < 16; ++i)
        #pragma unroll
        for (int j = 0; j < 8; ++j) acc[i][j] = 0.0f;

    for (int kc = 0; kc < 12; ++kc) {
        const int kb = kBase + kc * 32;
        #pragma unroll
        for (int m = 0; m < 4; ++m) {
            int flat = m * 256 + tid;
            int r = flat >> 3, i4 = flat & 7;
            float4 v = *(const float4*)(x + (size_t)(rowsBase + r) * ND + kb + i4 * 4);
            xs[i4*4+0][r] = v.x; xs[i4*4+1][r] = v.y;
            xs[i4*4+2][r] = v.z; xs[i4*4+3][r] = v.w;
        }
        #pragma unroll
        for (int m = 0; m < 8; ++m) {
            int flat = m * 256 + tid;
            int k = flat >> 6, c = (flat & 63) * 4;
            *(float4*)&ws[k][c] = *(const float4*)(w1 + (size_t)(kb + k) * 256 + c);
        }
        __syncthreads();
        #pragma unroll 4
        for (int k = 0; k < 32; ++k) {
            float xv[16], wv8[8];
            *(float4*)&xv[0]  = *(const float4*)&xs[k][r0w];
            *(float4*)&xv[4]  = *(const float4*)&xs[k][r0w + 4];
            *(float4*)&xv[8]  = *(const float4*)&xs[k][r0w + 8];
            *(float4*)&xv[12] = *(const float4*)&xs[k][r0w + 12];
            *(float4*)&wv8[0] = *(const float4*)&ws[k][c0];
            *(float4*)&wv8[4] = *(const float4*)&ws[k][c0 + 4];
            #pragma unroll
            for (int i = 0; i < 16; ++i)
                #pragma unroll
                for (int j = 0; j < 8; ++j)
                    acc[i][j] = fmaf(xv[i], wv8[j], acc[i][j]);
        }
        __syncthreads();
    }
    float* dst = u1p + (size_t)half * 8388608;
    #pragma unroll
    for (int i = 0; i < 16; ++i) {
        int row = rowsBase + r0w + i;
        *(float4*)(dst + (size_t)row * 256 + c0)     = *(float4*)&acc[i][0];
        *(float4*)(dst + (size_t)row * 256 + c0 + 4) = *(float4*)&acc[i][4];
    }
}

// ---------------------------------------------------------------------------
// k1_epi: h1 = gelu(LN(u1p0 + u1p1 + b1)); one wave per row
// ---------------------------------------------------------------------------
__global__ __launch_bounds__(256) void k1_epi(
    const float* __restrict__ u1p, const float* __restrict__ b1,
    const float* __restrict__ lng, const float* __restrict__ lnb,
    float* __restrict__ h1)
{
    const int wv = threadIdx.x >> 6, l = threadIdx.x & 63;
    const int row = blockIdx.x * 4 + wv;
    float4 a = *(const float4*)(u1p + (size_t)row * 256 + l * 4);
    float4 b = *(const float4*)(u1p + 8388608 + (size_t)row * 256 + l * 4);
    float4 bb = *(const float4*)(b1 + l * 4);
    float u[4] = {a.x + b.x + bb.x, a.y + b.y + bb.y,
                  a.z + b.z + bb.z, a.w + b.w + bb.w};
    float s = u[0] + u[1] + u[2] + u[3];
    float q = u[0]*u[0] + u[1]*u[1] + u[2]*u[2] + u[3]*u[3];
    #pragma unroll
    for (int o = 1; o < 64; o <<= 1) {
        s += __shfl_xor(s, o);
        q += __shfl_xor(q, o);
    }
    float mean = s * (1.0f / 256.0f);
    float var  = q * (1.0f / 256.0f) - mean * mean;
    float rstd = rsqrtf(var + 1e-5f);
    float4 g = *(const float4*)(lng + l * 4);
    float4 be = *(const float4*)(lnb + l * 4);
    float4 o;
    o.x = gelu_exact((u[0] - mean) * rstd * g.x + be.x);
    o.y = gelu_exact((u[1] - mean) * rstd * g.y + be.y);
    o.z = gelu_exact((u[2] - mean) * rstd * g.z + be.z);
    o.w = gelu_exact((u[3] - mean) * rstd * g.w + be.w);
    *(float4*)(h1 + (size_t)row * 256 + l * 4) = o;
}

// ---------------------------------------------------------------------------
// k2a_p: partial u2 = h1[:, kh] @ w2[kh, :]  (fp32, K-split 2, no bias/act)
// 256 thr, tile 128x128, per-thread 8x8. grid 512.
// ---------------------------------------------------------------------------
__global__ __launch_bounds__(256) void k2a_p(
    const float* __restrict__ h1, const float* __restrict__ w2,
    float* __restrict__ u2p)
{
    __shared__ float xs[32][132];
    __shared__ float ws[32][128];

    const int tid = threadIdx.x;
    const int tc = tid & 15, tr = tid >> 4;
    const int c0 = tc * 4, c1 = 64 + tc * 4, r0 = tr * 8;
    const int rb = blockIdx.x >> 1, half = blockIdx.x & 1;
    const int rowsBase = rb * 128, kBase = half * 128;

    float acc[8][8];
    #pragma unroll
    for (int i = 0; i < 8; ++i)
        #pragma unroll
        for (int j = 0; j < 8; ++j) acc[i][j] = 0.0f;

    for (int kc = 0; kc < 4; ++kc) {
        const int kb = kBase + kc * 32;
        #pragma unroll
        for (int m = 0; m < 4; ++m) {
            int flat = m * 256 + tid;
            int r = flat >> 3, i4 = flat & 7;
            float4 v = *(const float4*)(h1 + (size_t)(rowsBase + r) * 256 + kb + i4 * 4);
            xs[i4*4+0][r] = v.x; xs[i4*4+1][r] = v.y;
            xs[i4*4+2][r] = v.z; xs[i4*4+3][r] = v.w;
        }
        #pragma unroll
        for (int m = 0; m < 4; ++m) {
            int flat = m * 256 + tid;
            int k = flat >> 5, c = (flat & 31) * 4;
            *(float4*)&ws[k][c] = *(const float4*)(w2 + (size_t)(kb + k) * 128 + c);
        }
        __syncthreads();
        #pragma unroll 8
        for (int k = 0; k < 32; ++k) {
            float xv[8], wv8[8];
            *(float4*)&xv[0]  = *(const float4*)&xs[k][r0];
            *(float4*)&xv[4]  = *(const float4*)&xs[k][r0 + 4];
            *(float4*)&wv8[0] = *(const float4*)&ws[k][c0];
            *(float4*)&wv8[4] = *(const float4*)&ws[k][c1];
            #pragma unroll
            for (int i = 0; i < 8; ++i)
                #pragma unroll
                for (int j = 0; j < 8; ++j)
                    acc[i][j] = fmaf(xv[i], wv8[j], acc[i][j]);
        }
        __syncthreads();
    }
    float* dst = u2p + (size_t)half * 4194304;
    #pragma unroll
    for (int i = 0; i < 8; ++i) {
        int row = rowsBase + r0 + i;
        *(float4*)(dst + (size_t)row * 128 + c0) = *(float4*)&acc[i][0];
        *(float4*)(dst + (size_t)row * 128 + c1) = *(float4*)&acc[i][4];
    }
}

// ---------------------------------------------------------------------------
// mfma_gemm: out = act(A[M,K] @ W[K,N] + bias) via bf16 split-3 MFMA.
// 256 thr = 4 waves (2x2), tile 128x128, wave 64x64 = 4x4 frags of 16x16x32.
// A-frag: lane holds A[row = l&15][k = (l>>4)*8 + j]; B-frag symmetric.
// C/D: col = l&15, row = (l>>4)*4 + reg  [verified layout].
// ACT: 0 = gelu, 1 = sigmoid
// ---------------------------------------------------------------------------
template<int ACT>
__global__ __launch_bounds__(256) void mfma_gemm(
    const float* __restrict__ A, const float* __restrict__ W,
    const float* __restrict__ bias, float* __restrict__ out,
    int N, int K, int colBlocks)
{
    __shared__ short Ah[128][32];
    __shared__ short Al[128][32];
    __shared__ short Bh[4][128][8];
    __shared__ short Bl[4][128][8];

    const int tid = threadIdx.x;
    const int l = tid & 63;
    const int w = tid >> 6;
    const int wm = w >> 1, wn = w & 1;
    const int lg = l >> 4, lr = l & 15;
    const int rb = blockIdx.x / colBlocks;
    const int cb = blockIdx.x - rb * colBlocks;
    const int rowsBase = rb * 128, colBase = cb * 128;

    f32x4 zero = {0.0f, 0.0f, 0.0f, 0.0f};
    f32x4 acc[4][4];
    #pragma unroll
    for (int mi = 0; mi < 4; ++mi)
        #pragma unroll
        for (int ni = 0; ni < 4; ++ni) acc[mi][ni] = zero;

    // B-staging thread roles
    const int oct = tid >> 6;
    const int bidx = tid & 63;
    const int colq = bidx >> 1, hh = bidx & 1;
    const int cA = colq * 4 + hh * 2;

    for (int kb = 0; kb < K; kb += 32) {
        // stage A: 128 rows x 32 k as hi/lo bf16, [row][k] k-contiguous
        #pragma unroll
        for (int cc = 0; cc < 2; ++cc) {
            int cell = tid * 2 + cc;
            int row = cell >> 2, oc = cell & 3;
            const float* src = A + (size_t)(rowsBase + row) * K + kb + oc * 8;
            float4 v0 = *(const float4*)src;
            float4 v1 = *(const float4*)(src + 4);
            float f[8] = {v0.x, v0.y, v0.z, v0.w, v1.x, v1.y, v1.z, v1.w};
            short8_t ph, pl;
            #pragma unroll
            for (int j = 0; j < 8; ++j) {
                short hi, lo; f2bf2(f[j], hi, lo);
                ph[j] = hi; pl[j] = lo;
            }
            *(short8_t*)&Ah[row][oc * 8] = ph;
            *(short8_t*)&Al[row][oc * 8] = pl;
        }
        // stage B transposed: [oct][col][8 k] hi/lo; thread covers 2 cols
        {
            short8_t h0, l0, h1v, l1v;
            #pragma unroll
            for (int j = 0; j < 8; ++j) {
                float2 v = *(const float2*)(W + (size_t)(kb + oct * 8 + j) * N
                                            + colBase + cA);
                short hi, lo;
                f2bf2(v.x, hi, lo); h0[j] = hi; l0[j] = lo;
                f2bf2(v.y, hi, lo); h1v[j] = hi; l1v[j] = lo;
            }
            *(short8_t*)&Bh[oct][cA][0]     = h0;
            *(short8_t*)&Bl[oct][cA][0]     = l0;
            *(short8_t*)&Bh[oct][cA + 1][0] = h1v;
            *(short8_t*)&Bl[oct][cA + 1][0] = l1v;
        }
        __syncthreads();

        short8_t afh[4], afl[4], bfh[4], bfl[4];
        #pragma unroll
        for (int mi = 0; mi < 4; ++mi) {
            int row = wm * 64 + mi * 16 + lr;
            afh[mi] = *(const short8_t*)&Ah[row][lg * 8];
            afl[mi] = *(const short8_t*)&Al[row][lg * 8];
        }
        #pragma unroll
        for (int ni = 0; ni < 4; ++ni) {
            int col = wn * 64 + ni * 16 + lr;
            bfh[ni] = *(const short8_t*)&Bh[lg][col][0];
            bfl[ni] = *(const short8_t*)&Bl[lg][col][0];
        }
        #pragma unroll
        for (int mi = 0; mi < 4; ++mi)
            #pragma unroll
            for (int ni = 0; ni < 4; ++ni) {
                acc[mi][ni] = __builtin_amdgcn_mfma_f32_16x16x32_bf16(
                    afl[mi], bfh[ni], acc[mi][ni], 0, 0, 0);
                acc[mi][ni] = __builtin_amdgcn_mfma_f32_16x16x32_bf16(
                    afh[mi], bfl[ni], acc[mi][ni], 0, 0, 0);
                acc[mi][ni] = __builtin_amdgcn_mfma_f32_16x16x32_bf16(
                    afh[mi], bfh[ni], acc[mi][ni], 0, 0, 0);
            }
        __syncthreads();
    }

    // epilogue: D col = l&15, row = (l>>4)*4 + reg
    #pragma unroll
    for (int ni = 0; ni < 4; ++ni) {
        int col = colBase + wn * 64 + ni * 16 + lr;
        float bv = bias[col];
        #pragma unroll
        for (int mi = 0; mi < 4; ++mi) {
            #pragma unroll
            for (int j = 0; j < 4; ++j) {
                int row = rowsBase + wm * 64 + mi * 16 + lg * 4 + j;
                float v = acc[mi][ni][j] + bv;
                v = (ACT == 0) ? gelu_exact(v) : sigmoidf_(v);
                out[(size_t)row * N + col] = v;
            }
        }
    }
}

// ---------------------------------------------------------------------------
// k3: h2 = gelu(u2p0+u2p1+b2) in-reg; logits = h2@w3 + b3 + gi; probs;
// constrained selection -> sel; scalar partials.
// scal: [0]=active_groups [1..8]=group_usage [9]=load_balance [10]=active_dims
// ---------------------------------------------------------------------------
__global__ __launch_bounds__(128) void k3_router(
    const float* __restrict__ u2p, const float* __restrict__ w3,
    const float* __restrict__ b3, const float* __restrict__ gi,
    const float* __restrict__ b2, float* __restrict__ probsOut,
    float* __restrict__ selOut, float* __restrict__ scal)
{
    __shared__ float ws3[128][8];
    __shared__ float sAct[2], sP[2], sCnt[2][8];

    const int tid = threadIdx.x;
    *(float4*)&ws3[tid][0] = *(const float4*)(w3 + tid * 8);
    *(float4*)&ws3[tid][4] = *(const float4*)(w3 + tid * 8 + 4);
    __syncthreads();

    const int row = blockIdx.x * 128 + tid;
    const float* r0p = u2p + (size_t)row * 128;
    const float* r1p = u2p + 4194304 + (size_t)row * 128;

    float accg[8];
    #pragma unroll
    for (int g = 0; g < 8; ++g) accg[g] = 0.0f;
    #pragma unroll 4
    for (int k4 = 0; k4 < 32; ++k4) {
        float4 a = *(const float4*)(r0p + k4 * 4);
        float4 b = *(const float4*)(r1p + k4 * 4);
        float4 bb = *(const float4*)(b2 + k4 * 4);
        float hv4[4];
        hv4[0] = gelu_exact(a.x + b.x + bb.x);
        hv4[1] = gelu_exact(a.y + b.y + bb.y);
        hv4[2] = gelu_exact(a.z + b.z + bb.z);
        hv4[3] = gelu_exact(a.w + b.w + bb.w);
        #pragma unroll
        for (int t = 0; t < 4; ++t)
            #pragma unroll
            for (int g = 0; g < 8; ++g)
                accg[g] = fmaf(hv4[t], ws3[k4 * 4 + t][g], accg[g]);
    }

    float p[8], gs[8], cnt[8];
    float actCnt = 0.0f, pSum = 0.0f;
    #pragma unroll
    for (int g = 0; g < 8; ++g) {
        float lg = accg[g] + b3[g] + gi[g];
        p[g] = sigmoidf_(lg);
    }
    #pragma unroll
    for (int g = 0; g < 8; ++g) {
        int rank = 0;
        #pragma unroll
        for (int j = 0; j < 8; ++j) {
            rank += (p[j] > p[g]) ? 1 : 0;
            rank += (j < g && p[j] == p[g]) ? 1 : 0;
        }
        float act = (rank < 2) ? 1.0f
                  : ((rank < 6) ? ((p[g] > 0.5f) ? 1.0f : 0.0f) : 0.0f);
        gs[g] = (act - p[g]) + p[g];
        float over = (p[g] > 0.5f) ? 1.0f : 0.0f;
        cnt[g] = over;
        actCnt += over;
        pSum += p[g];
    }

    *(float4*)(probsOut + (size_t)row * 8)     = *(float4*)&p[0];
    *(float4*)(probsOut + (size_t)row * 8 + 4) = *(float4*)&p[4];
    *(float4*)(selOut   + (size_t)row * 8)     = *(float4*)&gs[0];
    *(float4*)(selOut   + (size_t)row * 8 + 4) = *(float4*)&gs[4];

    #pragma unroll
    for (int o = 32; o > 0; o >>= 1) {
        actCnt += __shfl_down(actCnt, o);
        pSum   += __shfl_down(pSum, o);
        #pragma unroll
        for (int g = 0; g < 8; ++g) cnt[g] += __shfl_down(cnt[g], o);
    }
    if ((tid & 63) == 0) {
        int w = tid >> 6;
        sAct[w] = actCnt; sP[w] = pSum;
        #pragma unroll
        for (int g = 0; g < 8; ++g) sCnt[w][g] = cnt[g];
    }
    __syncthreads();
    if (tid == 0) {
        const float invB = 1.0f / 32768.0f;
        atomicAdd(&scal[0], (sAct[0] + sAct[1]) * invB);
        atomicAdd(&scal[9], (sP[0] + sP[1]) * invB);
        #pragma unroll
        for (int g = 0; g < 8; ++g)
            atomicAdd(&scal[1 + g], (sCnt[0][g] + sCnt[1][g]) * invB);
    }
}

// ---------------------------------------------------------------------------
// k4: gmask = repeat(sel); mask = gmask * dwts; active_dims reduce
// ---------------------------------------------------------------------------
__global__ __launch_bounds__(256) void k4_mask(
    const float* __restrict__ sel, const float* __restrict__ dwts,
    float* __restrict__ gmaskOut, float* __restrict__ maskOut,
    float* __restrict__ activeDims)
{
    const int stride = gridDim.x * 256;
    float cntF = 0.0f;
    for (int i4 = blockIdx.x * 256 + threadIdx.x; i4 < 6291456; i4 += stride) {
        int row = i4 / 192;
        int rem = i4 - row * 192;
        int g = rem / 24;
        float v = sel[(size_t)row * 8 + g];
        float4 d = *(const float4*)(dwts + (size_t)i4 * 4);
        float4 gm = {v, v, v, v};
        float4 m = {v * d.x, v * d.y, v * d.z, v * d.w};
        *(float4*)(gmaskOut + (size_t)i4 * 4) = gm;
        *(float4*)(maskOut  + (size_t)i4 * 4) = m;
        cntF += (m.x > 0.5f ? 1.0f : 0.0f) + (m.y > 0.5f ? 1.0f : 0.0f)
              + (m.z > 0.5f ? 1.0f : 0.0f) + (m.w > 0.5f ? 1.0f : 0.0f);
    }
    #pragma unroll
    for (int o = 32; o > 0; o >>= 1) cntF += __shfl_down(cntF, o);
    __shared__ float sc[4];
    if ((threadIdx.x & 63) == 0) sc[threadIdx.x >> 6] = cntF;
    __syncthreads();
    if (threadIdx.x == 0)
        atomicAdd(activeDims, (sc[0] + sc[1] + sc[2] + sc[3]) * (1.0f / 32768.0f));
}

__global__ void kz_zero(float* s) { if (threadIdx.x < 11) s[threadIdx.x] = 0.0f; }

// ---------------------------------------------------------------------------
extern "C" void kernel_launch(void* const* d_in, const int* in_sizes, int n_in,
                              void* d_out, int out_size, void* d_ws, size_t ws_size,
                              hipStream_t stream)
{
    const float* x   = (const float*)d_in[0];
    const float* w1  = (const float*)d_in[1];
    const float* b1  = (const float*)d_in[2];
    const float* lng = (const float*)d_in[3];
    const float* lnb = (const float*)d_in[4];
    const float* w2  = (const float*)d_in[5];
    const float* b2  = (const float*)d_in[6];
    const float* w3  = (const float*)d_in[7];
    const float* b3  = (const float*)d_in[8];
    const float* dw1 = (const float*)d_in[9];
    const float* db1 = (const float*)d_in[10];
    const float* dw2 = (const float*)d_in[11];
    const float* db2 = (const float*)d_in[12];
    const float* gi  = (const float*)d_in[13];

    float* out   = (float*)d_out;
    float* mask  = out;                 // [B,768] output slot
    float* gmask = out + 25165824;      // [B,768] output slot
    float* dwts  = out + 50331648;      // [B,768] output slot
    float* probs = out + 75497472;      // [B,8]
    float* sel   = out + 75759616;      // [B,8]
    float* scal  = out + 76021760;      // 11 scalars

    // scratch: mask slot (dead until k4), gmask slot (dead until k4)
    float* u1p = mask;                  // [2][B][256] = 16777216 floats
    float* h1  = mask + 16777216;       // [B][256]    =  8388608 floats
    float* g1  = gmask;                 // [B][256]    =  8388608 floats
    float* u2p = gmask + 8388608;       // [2][B][128] =  8388608 floats

    kz_zero<<<dim3(1), dim3(64), 0, stream>>>(scal);
    // router path (fp32 exact)
    k1r_p<<<dim3(512), dim3(256), 0, stream>>>(x, w1, u1p);
    k1_epi<<<dim3(8192), dim3(256), 0, stream>>>(u1p, b1, lng, lnb, h1);
    k2a_p<<<dim3(512), dim3(256), 0, stream>>>(h1, w2, u2p);
    k3_router<<<dim3(256), dim3(128), 0, stream>>>(
        u2p, w3, b3, gi, b2, probs, sel, scal);
    // dim-importance path (bf16 split-3 MFMA; no hard thresholds nearby)
    mfma_gemm<0><<<dim3(512), dim3(256), 0, stream>>>(
        x, dw1, db1, g1, 256, 768, 2);
    mfma_gemm<1><<<dim3(1536), dim3(256), 0, stream>>>(
        g1, dw2, db2, dwts, 768, 256, 6);
    k4_mask<<<dim3(2048), dim3(256), 0, stream>>>(sel, dwts, gmask, mask, &scal[10]);
}